// Round 2
// baseline (80.890 us; speedup 1.0000x reference)
//
#include <hip/hip_runtime.h>
#include <math.h>

// Problem constants (fixed by setup_inputs: B=4, N=4096, D=3)
#define NPTS   4096
#define DCH    3
#define BATCH  4
#define UNITS  (2 * BATCH)        // (b, dir) pairs
#define GS     32                 // samples per block
#define SLOTS  8                  // sample slots per block
#define SPT    4                  // samples per thread (GS / SLOTS)
#define RS     32                 // ref splits per block
#define MBLK   256                // SLOTS * RS threads
#define NH8    (NPTS / 8)         // 512 h8-groups per channel in LDS
#define H8S    (NH8 / RS)         // 16 h8-groups per split
#define GRPS   (NPTS / GS)        // 128 sample groups per unit
#define G1     (UNITS * GRPS)     // 1024 blocks -> 4/CU, 16 waves/CU

typedef _Float16 h2 __attribute__((ext_vector_type(2)));
typedef _Float16 h8 __attribute__((ext_vector_type(8)));
typedef unsigned long long u64;
typedef unsigned int u32;

// ---------------------------------------------------------------------------
// SINGLE-kernel fusion (R2). R1 analysis: k1 math is only ~5.5us; dur 74.6us
// is dominated by the 40us harness poison fill plus ~25us of per-graph-node
// overhead across {fill, k1, k2}. So: one kernel, minimum node count.
//  - Each block owns (b, dir, 32 samples), scans ALL 4096 refs from LDS ->
//    finalizes dmin locally, computes GPS terms, one partial sum per block.
//  - No zero-init node, no atomics on out: block publishes its partial as a
//    self-validating pair {bits, ~bits} via agent-scope (cross-XCD-visible)
//    relaxed 8B atomic store into ws. Poison can't fake it (P==~P insoluble);
//    stale prior-iteration pairs are bit-identical (deterministic) -> safe.
//  - Block 0 polls the 1024 pairs (agent-scope loads; only IT waits -> no
//    grid barrier, no fence storm, no deadlock) and plain-stores out[0].
// Cost: direction-sharing given up (math ~5.5 -> ~8.5us); saves k2 + a node
// gap + 2MiB partial traffic.
// ---------------------------------------------------------------------------
__global__ __launch_bounds__(MBLK, 4)
void kfused(const float* __restrict__ a1, const float* __restrict__ a2,
            const float* __restrict__ alpha_p, const float* __restrict__ beta_p,
            u64* __restrict__ flags, float* __restrict__ out, float scale) {
    const int g    = blockIdx.x & (GRPS - 1);    // sample group 0..127
    const int unit = blockIdx.x >> 7;            // 0..7
    const int b    = unit >> 1;
    const int dir  = unit & 1;
    // dir 0: f12 -> samples = array2, refs = array1
    // dir 1: f21 -> samples = array1, refs = array2
    const float* samples = (dir ? a1 : a2) + (size_t)b * NPTS * DCH;
    const float* refs    = (dir ? a2 : a1) + (size_t)b * NPTS * DCH;

    __shared__ h8 lx8[NH8], ly8[NH8], lz8[NH8];   // 24 KiB (all 4096 refs)
    __shared__ _Float16 red[GS][RS];              // 2 KiB split-partials
    __shared__ float fred[4];

    // stage all refs: transpose xyzxyz... -> 3 channel arrays, f32->f16.
    // thread u packs refs 2u, 2u+1; consecutive threads -> consecutive LDS
    // dwords (conflict-free). 8 iterations of 6 loads (L1/L2-hot: inputs are
    // only 392 KiB total, shared by all blocks).
    for (int u = threadIdx.x; u < NPTS / 2; u += MBLK) {
        const float* r = refs + 6 * u;
        h2 x, y, z;
        x.x = (_Float16)r[0]; x.y = (_Float16)r[3];
        y.x = (_Float16)r[1]; y.y = (_Float16)r[4];
        z.x = (_Float16)r[2]; z.y = (_Float16)r[5];
        ((h2*)lx8)[u] = x; ((h2*)ly8)[u] = y; ((h2*)lz8)[u] = z;
    }

    const int slot  = threadIdx.x & (SLOTS - 1);  // 0..7 sample slot
    const int split = threadIdx.x >> 3;           // 0..31 ref split

    h2 sx[SPT], sy[SPT], sz[SPT], rmin[SPT];
    #pragma unroll
    for (int j = 0; j < SPT; ++j) {
        const int m = g * GS + slot + SLOTS * j;
        sx[j] = (h2)((_Float16)samples[3 * m + 0]);   // splat
        sy[j] = (h2)((_Float16)samples[3 * m + 1]);
        sz[j] = (h2)((_Float16)samples[3 * m + 2]);
        rmin[j] = (h2)((_Float16)65504.0f);
    }
    __syncthreads();

    // main loop: this thread scans its 128-ref split for its 4 samples.
    // per h8-iter: 3 ds_read_b128 amortized over 160 VALU -> VALU-bound.
    const int h0 = split * H8S;
    #pragma unroll 4
    for (int n8 = 0; n8 < H8S; ++n8) {
        const h8 hx = lx8[h0 + n8];
        const h8 hy = ly8[h0 + n8];
        const h8 hz = lz8[h0 + n8];
        #define QSTEP(q)                                                     \
        {                                                                    \
            const h2 rx = __builtin_shufflevector(hx, hx, 2*(q), 2*(q)+1);   \
            const h2 ry = __builtin_shufflevector(hy, hy, 2*(q), 2*(q)+1);   \
            const h2 rz = __builtin_shufflevector(hz, hz, 2*(q), 2*(q)+1);   \
            _Pragma("unroll")                                                \
            for (int j = 0; j < SPT; ++j) {                                  \
                h2 dx = __builtin_elementwise_abs(sx[j] - rx);               \
                h2 dy = __builtin_elementwise_abs(sy[j] - ry);               \
                h2 dz = __builtin_elementwise_abs(sz[j] - rz);               \
                h2 L  = dx + dy + dz;                                        \
                rmin[j] = __builtin_elementwise_min(rmin[j], L);             \
            }                                                                \
        }
        QSTEP(0) QSTEP(1) QSTEP(2) QSTEP(3)
        #undef QSTEP
    }

    // per-thread split-partials -> LDS
    #pragma unroll
    for (int j = 0; j < SPT; ++j) {
        const h2 d = rmin[j];
        red[slot + SLOTS * j][split] = (d.x < d.y) ? d.x : d.y;
    }
    __syncthreads();

    // threads 0..31: finalize dmin over 32 splits, GPS term
    float part = 0.0f;
    if (threadIdx.x < GS) {
        const h8* row = (const h8*)&red[threadIdx.x][0];
        h8 m8 = __builtin_elementwise_min(
                    __builtin_elementwise_min(row[0], row[1]),
                    __builtin_elementwise_min(row[2], row[3]));
        _Float16 dh = m8[0];
        #pragma unroll
        for (int k = 1; k < 8; ++k) dh = (m8[k] < dh) ? m8[k] : dh;
        const float dmin = (float)dh;

        const float alpha = alpha_p[0];
        const float beta  = beta_p[0];
        const float delta = powf(alpha, -1.0f / beta);
        const float s = alpha * exp2f(beta * log2f(dmin)) + delta;  // dmin>0
        part = -s * expf(-s);
    }
    // wave-0 sum (lanes 32..63 contribute 0)
    #pragma unroll
    for (int off = 32; off > 0; off >>= 1)
        part += __shfl_down(part, off, 64);

    if (threadIdx.x == 0) {
        const u32 bits = __float_as_uint(part);
        const u64 pair = ((u64)(~bits) << 32) | (u64)bits;   // self-validating
        __hip_atomic_store(&flags[blockIdx.x], pair,
                           __ATOMIC_RELAXED, __HIP_MEMORY_SCOPE_AGENT);
    }

    // block 0: combine all 1024 partials, write the scalar result
    if (blockIdx.x == 0) {
        float acc = 0.0f;
        for (int idx = threadIdx.x; idx < G1; idx += MBLK) {   // 4 each
            u64 v;
            for (;;) {
                v = __hip_atomic_load(&flags[idx],
                                      __ATOMIC_RELAXED, __HIP_MEMORY_SCOPE_AGENT);
                if ((u32)(v >> 32) == ~(u32)v) break;
                __builtin_amdgcn_s_sleep(2);
            }
            acc += __uint_as_float((u32)v);
        }
        #pragma unroll
        for (int off = 32; off > 0; off >>= 1)
            acc += __shfl_down(acc, off, 64);
        if ((threadIdx.x & 63) == 0) fred[threadIdx.x >> 6] = acc;
        __syncthreads();
        if (threadIdx.x == 0)
            out[0] = (fred[0] + fred[1] + fred[2] + fred[3]) * scale;
    }
}

extern "C" void kernel_launch(void* const* d_in, const int* in_sizes, int n_in,
                              void* d_out, int out_size, void* d_ws, size_t ws_size,
                              hipStream_t stream) {
    const float* a1    = (const float*)d_in[0];
    const float* a2    = (const float*)d_in[1];
    const float* alpha = (const float*)d_in[2];
    const float* beta  = (const float*)d_in[3];
    float* out = (float*)d_out;
    u64* flags = (u64*)d_ws;                        // 1024 * 8 B = 8 KiB

    const int B = in_sizes[0] / (NPTS * DCH);       // 4
    const float scale = 100.0f * 0.5f / (float)B;   // 12.5

    kfused<<<G1, MBLK, 0, stream>>>(a1, a2, alpha, beta, flags, out, scale);
}

// Round 3
// 74.239 us; speedup vs baseline: 1.0896x; 1.0896x over previous
//
#include <hip/hip_runtime.h>
#include <math.h>

// Problem constants (fixed by setup_inputs: B=4, N=4096, D=3)
#define NPTS   4096
#define DCH    3
#define JT     64              // j-tile: a2 refs staged in LDS per block
#define JB     (NPTS / JT)     // 64 j-blocks
#define IT     1024            // i-tile: a1 samples per block
#define IB     (NPTS / IT)     // 4 i-blocks
#define SPT    4               // i-samples per thread
#define MBLK   256
#define BATCH  4
#define G1     (BATCH * IB * JB)   // 1024 blocks -> 4/CU, 16 waves/CU
#define G2     (8 * 16)            // 128 combine blocks

typedef _Float16 h2 __attribute__((ext_vector_type(2)));
typedef _Float16 h8 __attribute__((ext_vector_type(8)));

// ---------------------------------------------------------------------------
// R3 = revert to R1 (best measured: 74.597us, absmax 0.0).
// R2's single-kernel fusion removed a node+gap yet regressed +6.3us ->
// the fixed ~68us is harness fill/reset overhead, NOT per-node gaps.
// dur_us tracks kernel time ~1:1; R1's kernels (~7us) are within ~2us of
// the VALU floor (67M shared distances ~= 3.5us math + reduce + k2).
//
// Direction-sharing: per batch, D[i][j] = L1(a1_i, a2_j) is the SAME matrix
// for f12 (col-mins over i) and f21 (row-mins over j). k1 computes each
// 1024x64 tile ONCE: row-min in registers, col-min in a 32-entry h2 register
// array (static indices via full unroll), block-reduced through LDS.
// k2 combines 64 row-partials (f21) or 4 col-partials (f12) + GPS + sum.
// ---------------------------------------------------------------------------
__global__ __launch_bounds__(MBLK, 4)
void k1(const float* __restrict__ a1, const float* __restrict__ a2,
        _Float16* __restrict__ rowp, _Float16* __restrict__ colp,
        float* __restrict__ out) {
    if (blockIdx.x == 0 && threadIdx.x == 0) out[0] = 0.0f;  // replaces memset

    const int jb = blockIdx.x & (JB - 1);        // 0..63
    const int ib = (blockIdx.x >> 6) & (IB - 1); // 0..3
    const int b  = blockIdx.x >> 8;              // 0..3
    const float* A1 = a1 + (size_t)b * NPTS * DCH;   // i side (f21 samples)
    const float* A2 = a2 + (size_t)b * NPTS * DCH;   // j side (f12 samples)

    __shared__ h8 lx8[JT / 8], ly8[JT / 8], lz8[JT / 8];
    __shared__ h2 lred[MBLK][33];   // col-min reduce scratch (+1 pad, 2-way free)

    {   // stage + transpose + f32->f16: threads 0..31 each pack 2 refs
        const int i = threadIdx.x;
        if (i < JT / 2) {
            const float* r = A2 + (size_t)jb * JT * DCH + 6 * i;
            h2 x, y, z;
            x.x = (_Float16)r[0]; x.y = (_Float16)r[3];
            y.x = (_Float16)r[1]; y.y = (_Float16)r[4];
            z.x = (_Float16)r[2]; z.y = (_Float16)r[5];
            ((h2*)lx8)[i] = x; ((h2*)ly8)[i] = y; ((h2*)lz8)[i] = z;
        }
    }

    const int m0 = ib * IT + threadIdx.x;
    h2 sx[SPT], sy[SPT], sz[SPT], rmin[SPT], cmin[JT / 2];
    #pragma unroll
    for (int j = 0; j < SPT; ++j) {
        const int m = m0 + j * MBLK;
        sx[j] = (h2)((_Float16)A1[3 * m + 0]);   // splat
        sy[j] = (h2)((_Float16)A1[3 * m + 1]);
        sz[j] = (h2)((_Float16)A1[3 * m + 2]);
        rmin[j] = (h2)((_Float16)65504.0f);
    }
    #pragma unroll
    for (int c = 0; c < JT / 2; ++c) cmin[c] = (h2)((_Float16)65504.0f);
    __syncthreads();

    // Full unroll (8 iters) keeps cmin indices compile-time (no scratch).
    #pragma unroll
    for (int n8 = 0; n8 < JT / 8; ++n8) {
        const h8 hx = lx8[n8];
        const h8 hy = ly8[n8];
        const h8 hz = lz8[n8];
        #define QSTEP(q)                                                     \
        {                                                                    \
            const h2 rx = __builtin_shufflevector(hx, hx, 2*(q), 2*(q)+1);   \
            const h2 ry = __builtin_shufflevector(hy, hy, 2*(q), 2*(q)+1);   \
            const h2 rz = __builtin_shufflevector(hz, hz, 2*(q), 2*(q)+1);   \
            _Pragma("unroll")                                                \
            for (int j = 0; j < SPT; ++j) {                                  \
                h2 dx = __builtin_elementwise_abs(sx[j] - rx);               \
                h2 dy = __builtin_elementwise_abs(sy[j] - ry);               \
                h2 dz = __builtin_elementwise_abs(sz[j] - rz);               \
                h2 L  = dx + dy + dz;                                        \
                rmin[j] = __builtin_elementwise_min(rmin[j], L);             \
                cmin[(n8)*4 + (q)] =                                         \
                    __builtin_elementwise_min(cmin[(n8)*4 + (q)], L);        \
            }                                                                \
        }
        QSTEP(0) QSTEP(1) QSTEP(2) QSTEP(3)
        #undef QSTEP
    }

    // f21 partial: row-min over this jb-tile -> rowp[b][jb][i]
    {
        _Float16* dst = rowp + ((size_t)(b * JB + jb)) * NPTS;
        #pragma unroll
        for (int j = 0; j < SPT; ++j) {
            const h2 d = rmin[j];
            dst[m0 + j * MBLK] = (d.x < d.y) ? d.x : d.y;
        }
    }

    // f12 partial: block-reduce cmin (256 threads x 32 h2 -> 32 h2)
    #pragma unroll
    for (int c = 0; c < JT / 2; ++c) lred[threadIdx.x][c] = cmin[c];
    __syncthreads();
    {
        const int c = threadIdx.x & 31;
        const int r = threadIdx.x >> 5;          // 8 row-groups of 32
        h2 m2 = lred[r * 32 + 0][c];
        #pragma unroll
        for (int k = 1; k < 32; ++k)
            m2 = __builtin_elementwise_min(m2, lred[r * 32 + k][c]);
        __syncthreads();
        lred[r][c] = m2;                         // 8x32 partials
    }
    __syncthreads();
    if (threadIdx.x < 32) {
        const int c = threadIdx.x;
        h2 m2 = lred[0][c];
        #pragma unroll
        for (int r = 1; r < 8; ++r)
            m2 = __builtin_elementwise_min(m2, lred[r][c]);
        // col-min partial for j = jb*64 + {2c, 2c+1}, this ib only
        ((h2*)(colp + ((size_t)(b * IB + ib)) * NPTS))[jb * 32 + c] = m2;
    }
}

__global__ __launch_bounds__(MBLK)
void k2(const _Float16* __restrict__ rowp, const _Float16* __restrict__ colp,
        const float* __restrict__ alpha_p, const float* __restrict__ beta_p,
        float* __restrict__ out, float scale) {
    const int p = blockIdx.x >> 4;        // 0..3: f12 (col), 4..7: f21 (row)
    const int g = blockIdx.x & 15;        // sample group
    const int m = g * 256 + threadIdx.x;

    const float alpha = alpha_p[0];
    const float beta  = beta_p[0];
    const float delta = powf(alpha, -1.0f / beta);

    _Float16 dh = (_Float16)65504.0f;
    if (p < 4) {                          // f12: combine 4 i-block partials
        const _Float16* src = colp + (size_t)p * IB * NPTS + m;
        #pragma unroll
        for (int k = 0; k < IB; ++k) {
            const _Float16 v = src[(size_t)k * NPTS];
            dh = (v < dh) ? v : dh;
        }
    } else {                              // f21: combine 64 j-block partials
        const _Float16* src = rowp + (size_t)(p - 4) * JB * NPTS + m;
        #pragma unroll
        for (int k = 0; k < JB; ++k) {
            const _Float16 v = src[(size_t)k * NPTS];
            dh = (v < dh) ? v : dh;
        }
    }
    const float dmin = (float)dh;

    const float s = alpha * exp2f(beta * log2f(dmin)) + delta;   // dmin > 0
    float acc = -s * expf(-s);

    for (int off = 32; off > 0; off >>= 1)
        acc += __shfl_down(acc, off, 64);

    __shared__ float red[4];
    if ((threadIdx.x & 63) == 0) red[threadIdx.x >> 6] = acc;
    __syncthreads();
    if (threadIdx.x == 0)
        atomicAdd(out, (red[0] + red[1] + red[2] + red[3]) * scale);
}

extern "C" void kernel_launch(void* const* d_in, const int* in_sizes, int n_in,
                              void* d_out, int out_size, void* d_ws, size_t ws_size,
                              hipStream_t stream) {
    const float* a1    = (const float*)d_in[0];
    const float* a2    = (const float*)d_in[1];
    const float* alpha = (const float*)d_in[2];
    const float* beta  = (const float*)d_in[3];
    float* out = (float*)d_out;

    _Float16* rowp = (_Float16*)d_ws;                       // 4*64*4096 fp16 = 2 MiB
    _Float16* colp = rowp + (size_t)BATCH * JB * NPTS;      // 4*4*4096 fp16 = 128 KiB

    const int B = in_sizes[0] / (NPTS * DCH);       // 4
    const float scale = 100.0f * 0.5f / (float)B;   // 12.5

    k1<<<G1, MBLK, 0, stream>>>(a1, a2, rowp, colp, out);
    k2<<<G2, MBLK, 0, stream>>>(rowp, colp, alpha, beta, out, scale);
}